// Round 2
// baseline (1312.140 us; speedup 1.0000x reference)
//
#include <hip/hip_runtime.h>
#include <stdint.h>

// Problem constants (reference: EMB=256, HID=1024, N_TRACKS=4096, SEQ=9, n_predict=12)
#define NTRK 4096
#define HIDN 1024
#define EMBN 256
#define KTOT 1280   // EMB + HID
#define NOUT 19     // 8 enc + 11 dec steps

typedef __attribute__((ext_vector_type(8))) short short8;
typedef __attribute__((ext_vector_type(4))) float f32x4;

typedef __attribute__((address_space(1))) const void GV;
typedef __attribute__((address_space(3))) void LV;

__device__ __forceinline__ uint16_t f2bf(float f) {
  uint32_t u = __float_as_uint(f);
  u += 0x7fffu + ((u >> 16) & 1u);   // round-to-nearest-even
  return (uint16_t)(u >> 16);
}
__device__ __forceinline__ float bf2f(uint16_t v) {
  return __uint_as_float(((uint32_t)v) << 16);
}
// precise (setup only)
__device__ __forceinline__ float sigm(float x) { return 1.0f / (1.0f + expf(-x)); }
// fast (hot paths): v_exp + v_rcp; error ~1e-6, margin is 5.5x
__device__ __forceinline__ float sigmf_(float x) {
  return __builtin_amdgcn_rcpf(1.0f + __expf(-x));
}
__device__ __forceinline__ float tanhf_(float x) {
  return 2.0f * __builtin_amdgcn_rcpf(1.0f + __expf(-2.0f * x)) - 1.0f;
}

// -------------------------------------------------------------------------
// Weight prep (16-unit gate groups): permuted row j' = q*64 + gate*16 + u16
// maps to original row gate*1024 + (q*16+u16). A 64-wide N-slab holds the
// 4 gates (i,f,g,o) of 16 hidden units -> LSTM pointwise is lane-local.
// Wih|Whh concatenated into one [4096][1280] bf16 row (single stride).
// -------------------------------------------------------------------------
__global__ __launch_bounds__(256) void prep_weights(
    const float* __restrict__ encWih, const float* __restrict__ encWhh,
    const float* __restrict__ encB,
    const float* __restrict__ decWih, const float* __restrict__ decWhh,
    const float* __restrict__ decB,
    uint16_t* __restrict__ WcatE, uint16_t* __restrict__ WcatD,
    float* __restrict__ biasE, float* __restrict__ biasD, float* __restrict__ biasDT)
{
  const int jp = blockIdx.x;                 // permuted row 0..4095
  const int q = jp >> 6, r = jp & 63;
  const int gate = r >> 4, l16 = r & 15;
  const int u = q * 16 + l16;
  const int orig = gate * 1024 + u;
  const int t = threadIdx.x;                 // 0..255

  WcatE[(size_t)jp * KTOT + t] = f2bf(encWih[(size_t)orig * 256 + t]);
  WcatD[(size_t)jp * KTOT + t] = f2bf(decWih[(size_t)orig * 256 + t]);
#pragma unroll
  for (int c = 0; c < 4; c++) {
    WcatE[(size_t)jp * KTOT + 256 + c * 256 + t] = f2bf(encWhh[(size_t)orig * 1024 + c * 256 + t]);
    WcatD[(size_t)jp * KTOT + 256 + c * 256 + t] = f2bf(decWhh[(size_t)orig * 1024 + c * 256 + t]);
  }
  if (t == 0) {
    biasE[jp]  = encB[orig];
    biasD[jp]  = decB[orig];
    biasDT[jp] = decB[orig] + decWih[(size_t)orig * 256 + 255]; // dec tag one-hot col 255
  }
}

// Enc-tag cell with h=c=0: gates identical for all tracks -> closed form.
__global__ void init_h0(const float* __restrict__ encWih, const float* __restrict__ encB,
                        float* __restrict__ h0, float* __restrict__ c0)
{
  const int u = blockIdx.x * 256 + threadIdx.x;   // 0..1023
  if (u >= 1024) return;
  const float gi = encWih[(size_t)(u) * 256 + 254]        + encB[u];
  const float gg = encWih[(size_t)(2048 + u) * 256 + 254] + encB[2048 + u];
  const float go = encWih[(size_t)(3072 + u) * 256 + 254] + encB[3072 + u];
  const float c = sigm(gi) * tanhf(gg);   // sigm(gf)*0 + ...
  c0[u] = c;
  h0[u] = sigm(go) * tanhf(c);
}

__global__ void fill_state(const float* __restrict__ h0, const float* __restrict__ c0,
                           uint16_t* __restrict__ H, float* __restrict__ Cst)
{
  const size_t i = (size_t)blockIdx.x * 256 + threadIdx.x;  // 4096*1024 total
  const int u = (int)(i & 1023);
  H[i] = f2bf(h0[u]);
  Cst[i] = c0[u];
}

// embed fallback for one encoder step (if workspace can't hold Xall)
__global__ __launch_bounds__(256) void embed_k(
    const float* __restrict__ o1, const float* __restrict__ o2,
    const float* __restrict__ ew, const float* __restrict__ eb,
    uint16_t* __restrict__ X)
{
  const int trk = blockIdx.x;
  const int j = threadIdx.x;
  const float vx = (o2[trk * 2]     - o1[trk * 2])     * 4.0f;
  const float vy = (o2[trk * 2 + 1] - o1[trk * 2 + 1]) * 4.0f;
  float e = 0.f;
  if (j < 254) e = fmaxf(vx * ew[j * 2] + vy * ew[j * 2 + 1] + eb[j], 0.f);
  X[(size_t)trk * 256 + j] = f2bf(e);
}

// All 8 encoder embeds in one dispatch (inputs known upfront).
__global__ __launch_bounds__(256) void embed8(
    const float* __restrict__ observed, const float* __restrict__ ew,
    const float* __restrict__ eb, uint16_t* __restrict__ Xall)
{
  const int t = blockIdx.y;          // 0..7
  const int trk = blockIdx.x;
  const int j = threadIdx.x;
  const float* o1 = observed + ((size_t)t * 4096 + trk) * 2;
  const float* o2 = o1 + 4096 * 2;
  const float vx = (o2[0] - o1[0]) * 4.0f;
  const float vy = (o2[1] - o1[1]) * 4.0f;
  float e = 0.f;
  if (j < 254) e = fmaxf(vx * ew[j * 2] + vy * ew[j * 2 + 1] + eb[j], 0.f);
  Xall[((size_t)t * 4096 + trk) * 256 + j] = f2bf(e);
}

// -------------------------------------------------------------------------
// Fused LSTM-cell GEMM — m201-style 8-phase schedule adapted to K=1280.
// 256x256 tile, 8 waves of 512 threads, BK=64, double-buffered LDS (128KB).
// Per K-tile: 4 phases, each = {ds_read frag-set || stage 1 half-tile ->
// barrier -> lgkmcnt(0) -> setprio(1) 16 MFMA setprio(0) -> counted
// vmcnt(4) -> barrier}. Wave's C-chunk rotates through the 4 (A-half,B-half)
// quadrant pairs: p0=(A0,B0) p1=(A1,B0) p2=(A1,B1) p3=(A0,B1) — so phase p
// needs only stage s<=p of this tile, enabling half-tile-granular prefetch:
//   stage order per tile: s0=A-h0, s1=B-h0, s2=A-h1, s3=B-h1 (2 loads/wave).
//   waits: vmcnt(4) at p0/p1/p3, none at p2; NEVER drained in the loop.
//   invariant: entering tile T, outstanding = {T.s2, T.s3}; each vmcnt(4)
//   retires exactly the half the NEXT phase's ds_reads need. Extra vmem ops
//   (e.g. smask loads) only make the waits stricter -> safe.
// Operand regs cached across phases (a0 p0/p3, a1 p1/p2, bf pairwise) ->
// 24 ds_read_b128/wave/K-tile (LDS ~2048cy < MFMA ~2483cy per CU per tile).
// Bank conflicts: XOR-chunk swizzle chunk^=row&7 (16B granule), applied as
// inverse-permuted GLOBAL source + swizzled ds_read; gload_lds dest linear
// (rule #21). Read slots then cover all 8 16B-positions, 2 lanes each (free).
// -------------------------------------------------------------------------
__global__ __launch_bounds__(512, 2) void gemm_lstm(
    const uint16_t* __restrict__ X,    const uint16_t* __restrict__ Hin,
    const uint16_t* __restrict__ Wcat, const float* __restrict__ bias,
    float* __restrict__ Cst,           uint16_t* __restrict__ Hout,
    const float* __restrict__ obs1,    const float* __restrict__ obs2,
    int k0, int maskmode)
{
  __shared__ uint16_t As[2 * 16384];   // [buf][256 rows][64 k]
  __shared__ uint16_t Bs[2 * 16384];
  __shared__ uint16_t Dm[512];         // dummy stage target (tail cadence)
  __shared__ uint8_t  smask[256];

  const int tid  = threadIdx.x;
  const int w    = tid >> 6;          // wave 0..7
  const int lane = tid & 63;
  const int qr   = w & 3;             // within-quadrant 32-row chunk
  const int qc   = w >> 2;            // within-quadrant 64-col half
  const int quad = lane >> 4;
  const int l15  = lane & 15;
  const int e7   = l15 & 7;

  // XCD-bijective swizzle: 256 blocks = 8 XCDs x 32 contiguous tiles
  const int bid = blockIdx.y * 16 + blockIdx.x;
  const int wg  = (bid & 7) * 32 + (bid >> 3);
  const int bm  = (wg >> 4) * 256;    // track rows
  const int bn  = (wg & 15) * 256;    // permuted gate cols

  const int NT = (KTOT - k0) >> 6;    // 20 (normal) or 16 (tag step)

  if (tid < 256) {
    bool m = true;
    if (maskmode) {
      const float a = obs1[(bm + tid) * 2];
      const float b = obs2[(bm + tid) * 2];
      m = !((a != a) || (b != b));
    }
    smask[tid] = m ? 1 : 0;
  }

  // Staging geometry: half-tile = 128 rows x 64 k (16 KB) = 2 gload_lds/wave.
  // Instr j covers rows base + w*16 + j*8 + (lane>>3), source chunk swizzled
  // by (lane&7)^(lane>>3) so that LDS(r, c) = G(r, c ^ (r&7)).
  const int srow = w * 16 + (lane >> 3);
  const int sch  = ((lane & 7) ^ (lane >> 3)) * 8;   // elements
  const uint16_t* pXr = X ? X + (size_t)(bm + srow) * 256 + sch : (const uint16_t*)0;
  const uint16_t* pHr = Hin  + (size_t)(bm + srow) * 1024 + sch;
  const uint16_t* pWr = Wcat + (size_t)(bn + srow) * (size_t)KTOT + sch;

  auto stage_half = [&](int V, int s) {   // s: 0=A-h0, 1=B-h0, 2=A-h1, 3=B-h1
    if (V >= NT) {                        // tail: keep vmcnt cadence exact
      const GV* dsrc = (GV*)(Wcat + (size_t)tid * 8);
      __builtin_amdgcn_global_load_lds(dsrc, (LV*)Dm, 16, 0, 0);
      __builtin_amdgcn_global_load_lds(dsrc, (LV*)Dm, 16, 0, 0);
      return;
    }
    const int kg = k0 + V * 64;
    const int h  = s >> 1;
    const bool isA = !(s & 1);
    uint16_t* dst = (isA ? As : Bs) + (V & 1) * 16384 + (h * 128 + w * 16) * 64;
    if (isA) {
      const bool inX = (kg < 256);
      const uint16_t* src0 = inX ? (pXr + (size_t)(h * 128) * 256 + kg)
                                 : (pHr + (size_t)(h * 128) * 1024 + (kg - 256));
      const int rs = inX ? 256 : 1024;
      __builtin_amdgcn_global_load_lds((GV*)src0,            (LV*)dst,            16, 0, 0);
      __builtin_amdgcn_global_load_lds((GV*)(src0 + 8 * rs), (LV*)(dst + 8 * 64), 16, 0, 0);
    } else {
      const uint16_t* src0 = pWr + (size_t)(h * 128) * (size_t)KTOT + kg;
      __builtin_amdgcn_global_load_lds((GV*)src0,              (LV*)dst,            16, 0, 0);
      __builtin_amdgcn_global_load_lds((GV*)(src0 + 8 * KTOT), (LV*)(dst + 8 * 64), 16, 0, 0);
    }
  };

  f32x4 acc[4][2][4];   // [phase][Mfrag][gate]
#pragma unroll
  for (int p = 0; p < 4; p++)
#pragma unroll
    for (int i = 0; i < 2; i++)
#pragma unroll
      for (int n = 0; n < 4; n++) acc[p][i][n] = (f32x4){0.f, 0.f, 0.f, 0.f};

  // prologue: stage tile 0 fully; land s0,s1; keep s2,s3 in flight
  stage_half(0, 0); stage_half(0, 1); stage_half(0, 2); stage_half(0, 3);
  asm volatile("s_waitcnt vmcnt(4)" ::: "memory");
  __builtin_amdgcn_s_barrier();

  const int arow = (qr * 32 + l15) * 64;   // +i*1024, +8192 for A-h1
  const int brow = (qc * 64 + l15) * 64;   // +n*1024, +8192 for B-h1
  const int cc0  = (quad ^ e7) * 8;        // swizzled chunk, ks=0
  const int cc1  = ((4 + quad) ^ e7) * 8;  // swizzled chunk, ks=1

  for (int T = 0; T < NT; T++) {
    const uint16_t* Ab = As + (T & 1) * 16384;
    const uint16_t* Bb = Bs + (T & 1) * 16384;
    short8 a0[2][2], a1[2][2], bf[4][2];

    // ---- phase 0: quadrant (A0,B0) ----
#pragma unroll
    for (int i = 0; i < 2; i++) {
      a0[i][0] = *(const short8*)(Ab + arow + i * 1024 + cc0);
      a0[i][1] = *(const short8*)(Ab + arow + i * 1024 + cc1);
    }
#pragma unroll
    for (int n = 0; n < 4; n++) {
      bf[n][0] = *(const short8*)(Bb + brow + n * 1024 + cc0);
      bf[n][1] = *(const short8*)(Bb + brow + n * 1024 + cc1);
    }
    stage_half(T + 1, 0);
    __builtin_amdgcn_s_barrier();
    asm volatile("s_waitcnt lgkmcnt(0)" ::: "memory");
    __builtin_amdgcn_sched_barrier(0);
    __builtin_amdgcn_s_setprio(1);
#pragma unroll
    for (int i = 0; i < 2; i++)
#pragma unroll
      for (int n = 0; n < 4; n++) {
        acc[0][i][n] = __builtin_amdgcn_mfma_f32_16x16x32_bf16(a0[i][0], bf[n][0], acc[0][i][n], 0, 0, 0);
        acc[0][i][n] = __builtin_amdgcn_mfma_f32_16x16x32_bf16(a0[i][1], bf[n][1], acc[0][i][n], 0, 0, 0);
      }
    __builtin_amdgcn_s_setprio(0);
    asm volatile("s_waitcnt vmcnt(4)" ::: "memory");   // retires this tile's A-h1
    __builtin_amdgcn_s_barrier();

    // ---- phase 1: quadrant (A1,B0) ----
#pragma unroll
    for (int i = 0; i < 2; i++) {
      a1[i][0] = *(const short8*)(Ab + 8192 + arow + i * 1024 + cc0);
      a1[i][1] = *(const short8*)(Ab + 8192 + arow + i * 1024 + cc1);
    }
    stage_half(T + 1, 1);
    __builtin_amdgcn_s_barrier();
    asm volatile("s_waitcnt lgkmcnt(0)" ::: "memory");
    __builtin_amdgcn_sched_barrier(0);
    __builtin_amdgcn_s_setprio(1);
#pragma unroll
    for (int i = 0; i < 2; i++)
#pragma unroll
      for (int n = 0; n < 4; n++) {
        acc[1][i][n] = __builtin_amdgcn_mfma_f32_16x16x32_bf16(a1[i][0], bf[n][0], acc[1][i][n], 0, 0, 0);
        acc[1][i][n] = __builtin_amdgcn_mfma_f32_16x16x32_bf16(a1[i][1], bf[n][1], acc[1][i][n], 0, 0, 0);
      }
    __builtin_amdgcn_s_setprio(0);
    asm volatile("s_waitcnt vmcnt(4)" ::: "memory");   // retires this tile's B-h1
    __builtin_amdgcn_s_barrier();

    // ---- phase 2: quadrant (A1,B1) ----
#pragma unroll
    for (int n = 0; n < 4; n++) {
      bf[n][0] = *(const short8*)(Bb + 8192 + brow + n * 1024 + cc0);
      bf[n][1] = *(const short8*)(Bb + 8192 + brow + n * 1024 + cc1);
    }
    stage_half(T + 1, 2);
    __builtin_amdgcn_s_barrier();
    asm volatile("s_waitcnt lgkmcnt(0)" ::: "memory");
    __builtin_amdgcn_sched_barrier(0);
    __builtin_amdgcn_s_setprio(1);
#pragma unroll
    for (int i = 0; i < 2; i++)
#pragma unroll
      for (int n = 0; n < 4; n++) {
        acc[2][i][n] = __builtin_amdgcn_mfma_f32_16x16x32_bf16(a1[i][0], bf[n][0], acc[2][i][n], 0, 0, 0);
        acc[2][i][n] = __builtin_amdgcn_mfma_f32_16x16x32_bf16(a1[i][1], bf[n][1], acc[2][i][n], 0, 0, 0);
      }
    __builtin_amdgcn_s_setprio(0);
    __builtin_amdgcn_s_barrier();                      // no vmcnt here

    // ---- phase 3: quadrant (A0,B1) — all operands cached ----
    stage_half(T + 1, 3);
    __builtin_amdgcn_s_barrier();
    __builtin_amdgcn_s_setprio(1);
#pragma unroll
    for (int i = 0; i < 2; i++)
#pragma unroll
      for (int n = 0; n < 4; n++) {
        acc[3][i][n] = __builtin_amdgcn_mfma_f32_16x16x32_bf16(a0[i][0], bf[n][0], acc[3][i][n], 0, 0, 0);
        acc[3][i][n] = __builtin_amdgcn_mfma_f32_16x16x32_bf16(a0[i][1], bf[n][1], acc[3][i][n], 0, 0, 0);
      }
    __builtin_amdgcn_s_setprio(0);
    asm volatile("s_waitcnt vmcnt(4)" ::: "memory");   // retires next tile's s0,s1
    __builtin_amdgcn_s_barrier();
  }
  asm volatile("s_waitcnt vmcnt(0)" ::: "memory");     // drain tail dummies once

  // Epilogue: per phase p, wave's C-chunk = rows ah*128+qr*32..+32,
  // cols bh*128+qc*64..+64 (n = gate). C/D: col=lane&15, row=quad*4+reg [m89]
#pragma unroll
  for (int p = 0; p < 4; p++) {
    const int ah = (p == 1 || p == 2) ? 1 : 0;
    const int bh = p >> 1;
    const int u  = ((bn >> 6) + bh * 2 + qc) * 16 + l15;
    const int jb = bn + bh * 128 + qc * 64 + l15;
    const float b_i = bias[jb];
    const float b_f = bias[jb + 16];
    const float b_g = bias[jb + 32];
    const float b_o = bias[jb + 48];
#pragma unroll
    for (int i = 0; i < 2; i++) {
#pragma unroll
      for (int r = 0; r < 4; r++) {
        const int row = bm + ah * 128 + qr * 32 + i * 16 + quad * 4 + r;
        const size_t idx = (size_t)row * 1024 + u;
        uint16_t hv;
        if (smask[row - bm]) {
          const float gi = acc[p][i][0][r] + b_i;
          const float gf = acc[p][i][1][r] + b_f;
          const float gg = acc[p][i][2][r] + b_g;
          const float go = acc[p][i][3][r] + b_o;
          const float cn = sigmf_(gf) * Cst[idx] + sigmf_(gi) * tanhf_(gg);
          Cst[idx] = cn;
          hv = f2bf(sigmf_(go) * tanhf_(cn));
        } else {
          hv = Hin[idx];        // state frozen; Hout is a different buffer
        }
        Hout[idx] = hv;
      }
    }
  }
}

// -------------------------------------------------------------------------
// h2n + outputs (+ optional fused embed for the NEXT step's X):
// raw = h @ h2n_w.T + h2n_b (one wave per track). Butterfly reduce leaves the
// full sums in ALL lanes; lane0 writes outputs; all lanes embed next X.
// -------------------------------------------------------------------------
__global__ __launch_bounds__(256) void h2n_pos(
    const uint16_t* __restrict__ H, const float* __restrict__ w5, const float* __restrict__ b5,
    const float* __restrict__ obs1, const float* __restrict__ obs2,
    float* __restrict__ outrel, float* __restrict__ outpos,
    const float* __restrict__ pprev, const float* __restrict__ ew,
    const float* __restrict__ eb, uint16_t* __restrict__ Xnext, int do_embed)
{
  const int lane  = threadIdx.x & 63;
  const int track = blockIdx.x * 4 + (threadIdx.x >> 6);

  const uint16_t* hrow = H + (size_t)track * 1024 + lane * 16;
  const short8 v0 = *(const short8*)(hrow);
  const short8 v1 = *(const short8*)(hrow + 8);
  float hv[16];
#pragma unroll
  for (int j = 0; j < 8; j++) {
    hv[j]     = bf2f((uint16_t)v0[j]);
    hv[8 + j] = bf2f((uint16_t)v1[j]);
  }
  const int kb = lane * 16;
  float p[5];
#pragma unroll
  for (int o = 0; o < 5; o++) {
    const float* wr = w5 + (size_t)o * 1024 + kb;
    float s = 0.f;
#pragma unroll
    for (int j = 0; j < 16; j++) s += hv[j] * wr[j];
    p[o] = s;
  }
#pragma unroll
  for (int o = 0; o < 5; o++) {
    float v = p[o];
    v += __shfl_xor(v, 32); v += __shfl_xor(v, 16); v += __shfl_xor(v, 8);
    v += __shfl_xor(v, 4);  v += __shfl_xor(v, 2);  v += __shfl_xor(v, 1);
    p[o] = v;
  }
  // all lanes hold the full sums now
  const float o1x = obs1[track * 2];
  const float o2x = obs2[track * 2];
  const float o2y = obs2[track * 2 + 1];
  const bool msk = !((o1x != o1x) || (o2x != o2x));
  float n0 = p[0] + b5[0];
  float n1 = p[1] + b5[1];
  float n2 = 0.01f + 0.2f * sigmf_(p[2] + b5[2]);
  float n3 = 0.01f + 0.2f * sigmf_(p[3] + b5[3]);
  float n4 = 0.7f  * sigmf_(p[4] + b5[4]);
  if (!msk) {
    const float qn = __uint_as_float(0x7fc00000u);
    n0 = n1 = n2 = n3 = n4 = qn;
  }
  const float posx = o2x + n0;
  const float posy = o2y + n1;
  if (lane == 0) {
    float* rr = outrel + (size_t)track * 5;
    rr[0] = n0; rr[1] = n1; rr[2] = n2; rr[3] = n3; rr[4] = n4;
    outpos[track * 2]     = posx;
    outpos[track * 2 + 1] = posy;
  }
  if (do_embed) {
    const float vx = (posx - pprev[track * 2])     * 4.0f;
    const float vy = (posy - pprev[track * 2 + 1]) * 4.0f;
    uint16_t* xr = Xnext + (size_t)track * 256;
#pragma unroll
    for (int ii = 0; ii < 4; ii++) {
      const int j = ii * 64 + lane;
      float e = 0.f;
      if (j < 254) e = fmaxf(vx * ew[j * 2] + vy * ew[j * 2 + 1] + eb[j], 0.f);
      xr[j] = f2bf(e);   // NaN inputs -> fmax gives 0; row is masked anyway
    }
  }
}

// -------------------------------------------------------------------------
extern "C" void kernel_launch(void* const* d_in, const int* in_sizes, int n_in,
                              void* d_out, int out_size, void* d_ws, size_t ws_size,
                              hipStream_t stream)
{
  const float* observed = (const float*)d_in[0];
  const float* emb_w    = (const float*)d_in[1];
  const float* emb_b    = (const float*)d_in[2];
  const float* enc_wih  = (const float*)d_in[3];
  const float* enc_whh  = (const float*)d_in[4];
  const float* enc_b    = (const float*)d_in[5];
  const float* dec_wih  = (const float*)d_in[6];
  const float* dec_whh  = (const float*)d_in[7];
  const float* dec_b    = (const float*)d_in[8];
  const float* h2n_w    = (const float*)d_in[9];
  const float* h2n_b    = (const float*)d_in[10];
  // d_in[11] = n_predict (==12, fixed by setup)

  char* ws = (char*)d_ws;
  size_t off = 0;
  auto alloc = [&](size_t bytes) -> void* {
    size_t cur = (off + 255) & ~(size_t)255;
    off = cur + bytes;
    return (void*)(ws + cur);
  };
  uint16_t* WcatE = (uint16_t*)alloc((size_t)4096 * KTOT * 2);
  uint16_t* WcatD = (uint16_t*)alloc((size_t)4096 * KTOT * 2);
  float*    biasE = (float*)alloc(4096 * 4);
  float*    biasD = (float*)alloc(4096 * 4);
  float*    biasDT= (float*)alloc(4096 * 4);
  float*    h0    = (float*)alloc(1024 * 4);
  float*    c0    = (float*)alloc(1024 * 4);
  uint16_t* HA    = (uint16_t*)alloc((size_t)4096 * 1024 * 2);
  uint16_t* HB    = (uint16_t*)alloc((size_t)4096 * 1024 * 2);
  float*    Cst   = (float*)alloc((size_t)4096 * 1024 * 4);
  uint16_t* Xb    = (uint16_t*)alloc((size_t)4096 * 256 * 2);
  // optional batched encoder X (16 MB) — only if workspace allows
  const size_t xall_bytes = (size_t)8 * 4096 * 256 * 2;
  const bool use_xall = (off + 256 + xall_bytes) <= ws_size;
  uint16_t* Xall = use_xall ? (uint16_t*)alloc(xall_bytes) : nullptr;

  float* outrel = (float*)d_out;                     // (19, 4096, 5)
  float* outpos = outrel + (size_t)NOUT * 4096 * 5;  // (19, 4096, 2)

  prep_weights<<<4096, 256, 0, stream>>>(enc_wih, enc_whh, enc_b, dec_wih, dec_whh, dec_b,
                                         WcatE, WcatD, biasE, biasD, biasDT);
  init_h0<<<4, 256, 0, stream>>>(enc_wih, enc_b, h0, c0);
  fill_state<<<16384, 256, 0, stream>>>(h0, c0, HA, Cst);
  if (use_xall) {
    embed8<<<dim3(4096, 8), 256, 0, stream>>>(observed, emb_w, emb_b, Xall);
  }

  uint16_t* Hin = HA;
  uint16_t* Hout = HB;
  const dim3 ggrid(16, 16);

  // ---- encoder: 8 steps over observed pairs ----
  for (int t = 0; t < 8; t++) {
    const float* o1 = observed + (size_t)t * 4096 * 2;
    const float* o2 = observed + (size_t)(t + 1) * 4096 * 2;
    uint16_t* Xt = Xb;
    if (use_xall) {
      Xt = Xall + (size_t)t * 4096 * 256;
    } else {
      embed_k<<<4096, 256, 0, stream>>>(o1, o2, emb_w, emb_b, Xb);
    }
    gemm_lstm<<<ggrid, 512, 0, stream>>>(Xt, Hin, WcatE, biasE, Cst, Hout, o1, o2, 0, 1);
    const int de = (t == 7) ? 1 : 0;   // t==7 also embeds X for first decoder step
    h2n_pos<<<1024, 256, 0, stream>>>(Hout, h2n_w, h2n_b, o1, o2,
                                      outrel + (size_t)t * 4096 * 5,
                                      outpos + (size_t)t * 4096 * 2,
                                      outpos + (size_t)6 * 4096 * 2, emb_w, emb_b, Xb, de);
    uint16_t* tmp = Hin; Hin = Hout; Hout = tmp;
  }

  // ---- decoder tag cell (x one-hot folded into biasDT; k0=256 skips X) ----
  gemm_lstm<<<ggrid, 512, 0, stream>>>(nullptr, Hin, WcatD, biasDT, Cst, Hout,
                                       nullptr, nullptr, 256, 0);
  { uint16_t* tmp = Hin; Hin = Hout; Hout = tmp; }

  // ---- decoder: 11 steps; X comes from the previous step's fused h2n ----
  for (int s = 0; s < 11; s++) {
    const float* p1 = outpos + (size_t)(6 + s) * 4096 * 2;
    const float* p2 = outpos + (size_t)(7 + s) * 4096 * 2;
    gemm_lstm<<<ggrid, 512, 0, stream>>>(Xb, Hin, WcatD, biasD, Cst, Hout, p1, p2, 0, 1);
    const int de = (s < 10) ? 1 : 0;   // last step needs no next X
    h2n_pos<<<1024, 256, 0, stream>>>(Hout, h2n_w, h2n_b, p1, p2,
                                      outrel + (size_t)(8 + s) * 4096 * 5,
                                      outpos + (size_t)(8 + s) * 4096 * 2,
                                      p2, emb_w, emb_b, Xb, de);
    uint16_t* tmp = Hin; Hin = Hout; Hout = tmp;
  }
}

// Round 4
// 1235.675 us; speedup vs baseline: 1.0619x; 1.0619x over previous
//
#include <hip/hip_runtime.h>
#include <stdint.h>

// Problem constants (reference: EMB=256, HID=1024, N_TRACKS=4096, SEQ=9, n_predict=12)
#define NTRK 4096
#define HIDN 1024
#define EMBN 256
#define KTOT 1280   // EMB + HID
#define NOUT 19     // 8 enc + 11 dec steps

typedef __attribute__((ext_vector_type(8))) short short8;
typedef __attribute__((ext_vector_type(4))) float f32x4;

typedef __attribute__((address_space(1))) const void GV;
typedef __attribute__((address_space(3))) void LV;

__device__ __forceinline__ uint16_t f2bf(float f) {
  uint32_t u = __float_as_uint(f);
  u += 0x7fffu + ((u >> 16) & 1u);   // round-to-nearest-even
  return (uint16_t)(u >> 16);
}
__device__ __forceinline__ float bf2f(uint16_t v) {
  return __uint_as_float(((uint32_t)v) << 16);
}
// precise (setup only)
__device__ __forceinline__ float sigm(float x) { return 1.0f / (1.0f + expf(-x)); }
// fast (hot paths): v_exp + v_rcp; error ~1e-6, margin is 5.5x
__device__ __forceinline__ float sigmf_(float x) {
  return __builtin_amdgcn_rcpf(1.0f + __expf(-x));
}
__device__ __forceinline__ float tanhf_(float x) {
  return 2.0f * __builtin_amdgcn_rcpf(1.0f + __expf(-2.0f * x)) - 1.0f;
}

// -------------------------------------------------------------------------
// Weight prep (16-unit gate groups): permuted row j' = q*64 + gate*16 + u16
// maps to original row gate*1024 + (q*16+u16). A 64-wide N-slab holds the
// 4 gates (i,f,g,o) of 16 hidden units -> LSTM pointwise is lane-local.
// Wih|Whh concatenated into one [4096][1280] bf16 row (single stride).
// -------------------------------------------------------------------------
__global__ __launch_bounds__(256) void prep_weights(
    const float* __restrict__ encWih, const float* __restrict__ encWhh,
    const float* __restrict__ encB,
    const float* __restrict__ decWih, const float* __restrict__ decWhh,
    const float* __restrict__ decB,
    uint16_t* __restrict__ WcatE, uint16_t* __restrict__ WcatD,
    float* __restrict__ biasE, float* __restrict__ biasD, float* __restrict__ biasDT)
{
  const int jp = blockIdx.x;                 // permuted row 0..4095
  const int q = jp >> 6, r = jp & 63;
  const int gate = r >> 4, l16 = r & 15;
  const int u = q * 16 + l16;
  const int orig = gate * 1024 + u;
  const int t = threadIdx.x;                 // 0..255

  WcatE[(size_t)jp * KTOT + t] = f2bf(encWih[(size_t)orig * 256 + t]);
  WcatD[(size_t)jp * KTOT + t] = f2bf(decWih[(size_t)orig * 256 + t]);
#pragma unroll
  for (int c = 0; c < 4; c++) {
    WcatE[(size_t)jp * KTOT + 256 + c * 256 + t] = f2bf(encWhh[(size_t)orig * 1024 + c * 256 + t]);
    WcatD[(size_t)jp * KTOT + 256 + c * 256 + t] = f2bf(decWhh[(size_t)orig * 1024 + c * 256 + t]);
  }
  if (t == 0) {
    biasE[jp]  = encB[orig];
    biasD[jp]  = decB[orig];
    biasDT[jp] = decB[orig] + decWih[(size_t)orig * 256 + 255]; // dec tag one-hot col 255
  }
}

// Enc-tag cell with h=c=0: gates identical for all tracks -> closed form.
__global__ void init_h0(const float* __restrict__ encWih, const float* __restrict__ encB,
                        float* __restrict__ h0, float* __restrict__ c0)
{
  const int u = blockIdx.x * 256 + threadIdx.x;   // 0..1023
  if (u >= 1024) return;
  const float gi = encWih[(size_t)(u) * 256 + 254]        + encB[u];
  const float gg = encWih[(size_t)(2048 + u) * 256 + 254] + encB[2048 + u];
  const float go = encWih[(size_t)(3072 + u) * 256 + 254] + encB[3072 + u];
  const float c = sigm(gi) * tanhf(gg);   // sigm(gf)*0 + ...
  c0[u] = c;
  h0[u] = sigm(go) * tanhf(c);
}

__global__ void fill_state(const float* __restrict__ h0, const float* __restrict__ c0,
                           uint16_t* __restrict__ H, float* __restrict__ Cst)
{
  const size_t i = (size_t)blockIdx.x * 256 + threadIdx.x;  // 4096*1024 total
  const int u = (int)(i & 1023);
  H[i] = f2bf(h0[u]);
  Cst[i] = c0[u];
}

// embed fallback for one encoder step (if workspace can't hold Xall)
__global__ __launch_bounds__(256) void embed_k(
    const float* __restrict__ o1, const float* __restrict__ o2,
    const float* __restrict__ ew, const float* __restrict__ eb,
    uint16_t* __restrict__ X)
{
  const int trk = blockIdx.x;
  const int j = threadIdx.x;
  const float vx = (o2[trk * 2]     - o1[trk * 2])     * 4.0f;
  const float vy = (o2[trk * 2 + 1] - o1[trk * 2 + 1]) * 4.0f;
  float e = 0.f;
  if (j < 254) e = fmaxf(vx * ew[j * 2] + vy * ew[j * 2 + 1] + eb[j], 0.f);
  X[(size_t)trk * 256 + j] = f2bf(e);
}

// All 8 encoder embeds in one dispatch (inputs known upfront).
__global__ __launch_bounds__(256) void embed8(
    const float* __restrict__ observed, const float* __restrict__ ew,
    const float* __restrict__ eb, uint16_t* __restrict__ Xall)
{
  const int t = blockIdx.y;          // 0..7
  const int trk = blockIdx.x;
  const int j = threadIdx.x;
  const float* o1 = observed + ((size_t)t * 4096 + trk) * 2;
  const float* o2 = o1 + 4096 * 2;
  const float vx = (o2[0] - o1[0]) * 4.0f;
  const float vy = (o2[1] - o1[1]) * 4.0f;
  float e = 0.f;
  if (j < 254) e = fmaxf(vx * ew[j * 2] + vy * ew[j * 2 + 1] + eb[j], 0.f);
  Xall[((size_t)t * 4096 + trk) * 256 + j] = f2bf(e);
}

// -------------------------------------------------------------------------
// Fused LSTM-cell GEMM — 256x256 tile, 8 waves, BK=64, double-buffered LDS.
// R3: barriers cut 8 -> 3 per K-tile. Only the correctness barriers remain,
// each paired with a counted vmcnt that publishes a freshly staged half:
//   B1 (after p0 MFMA): vmcnt(4) -> this tile's A-h1 landed (all waves)
//   B2 (after p1 MFMA): vmcnt(4) -> this tile's B-h1 landed
//   B3 (after p2+p3 MFMA): vmcnt(4) -> next tile's s0,s1 landed
// All mid-phase lockstep barriers removed: waves drift up to ~a phase, so
// one wave's MFMA overlaps another's ds_read burst / lgkmcnt / stage.
// Race-freedom: every LDS read region is covered by the last correctness
// barrier (p0 reads s0/s1 <- B3 of T-1; p1 reads A-h1 <- B1; p2 reads
// B-h1 <- B2). Every staging write targets a region whose last reader
// drained its own lgkmcnt(0) before a common barrier that precedes the
// write (s0@p0 <- readers' p0(T-1) drain < B3(T-1); s2@p2 <- p1(T-1) < B1(T)).
// vmcnt cadence (4 half-stages x 2 loads/wave, dummy-padded at tail):
// entering T outstanding = {T.s2,T.s3}; each vmcnt(4) retires exactly the
// half the next phase needs; never drained in the loop.
// XCD mapping: XCD = (bmS>>3)*4 + (bnS>>2) -> each XCD owns 8 bm x 4 bn,
// weight panel/XCD = 2.56MB <= 4MB L2 and identical across all 20 steps.
// -------------------------------------------------------------------------
__global__ __launch_bounds__(512, 2) void gemm_lstm(
    const uint16_t* __restrict__ X,    const uint16_t* __restrict__ Hin,
    const uint16_t* __restrict__ Wcat, const float* __restrict__ bias,
    float* __restrict__ Cst,           uint16_t* __restrict__ Hout,
    const float* __restrict__ obs1,    const float* __restrict__ obs2,
    int k0, int maskmode)
{
  __shared__ uint16_t As[2 * 16384];   // [buf][256 rows][64 k]
  __shared__ uint16_t Bs[2 * 16384];
  __shared__ uint16_t Dm[512];         // dummy stage target (tail cadence)
  __shared__ uint8_t  smask[256];

  const int tid  = threadIdx.x;
  const int w    = tid >> 6;          // wave 0..7
  const int lane = tid & 63;
  const int qr   = w & 3;             // within-quadrant 32-row chunk
  const int qc   = w >> 2;            // within-quadrant 64-col half
  const int quad = lane >> 4;
  const int l15  = lane & 15;
  const int e7   = l15 & 7;

  // XCD-bijective mapping: xcd = bid&7 (round-robin dispatch), 32 tiles/XCD
  // arranged 8 bm-strips x 4 bn-strips -> weights L2-resident per XCD.
  const int bid = blockIdx.y * 16 + blockIdx.x;
  const int xcd = bid & 7;
  const int j   = bid >> 3;           // 0..31
  const int bmS = (xcd >> 2) * 8 + (j >> 2);
  const int bnS = (xcd & 3) * 4 + (j & 3);
  const int bm  = bmS * 256;          // track rows
  const int bn  = bnS * 256;          // permuted gate cols

  const int NT = (KTOT - k0) >> 6;    // 20 (normal) or 16 (tag step)

  if (tid < 256) {
    bool m = true;
    if (maskmode) {
      const float a = obs1[(bm + tid) * 2];
      const float b = obs2[(bm + tid) * 2];
      m = !((a != a) || (b != b));
    }
    smask[tid] = m ? 1 : 0;
  }

  // Staging geometry: half-tile = 128 rows x 64 k (16 KB) = 2 gload_lds/wave.
  // Instr j covers rows base + w*16 + j*8 + (lane>>3), source chunk swizzled
  // by (lane&7)^(lane>>3) so that LDS(r, c) = G(r, c ^ (r&7)).
  const int srow = w * 16 + (lane >> 3);
  const int sch  = ((lane & 7) ^ (lane >> 3)) * 8;   // elements
  const uint16_t* pXr = X ? X + (size_t)(bm + srow) * 256 + sch : (const uint16_t*)0;
  const uint16_t* pHr = Hin  + (size_t)(bm + srow) * 1024 + sch;
  const uint16_t* pWr = Wcat + (size_t)(bn + srow) * (size_t)KTOT + sch;

  auto stage_half = [&](int V, int s) {   // s: 0=A-h0, 1=B-h0, 2=A-h1, 3=B-h1
    if (V >= NT) {                        // tail: keep vmcnt cadence exact
      const GV* dsrc = (GV*)(Wcat + (size_t)tid * 8);
      __builtin_amdgcn_global_load_lds(dsrc, (LV*)Dm, 16, 0, 0);
      __builtin_amdgcn_global_load_lds(dsrc, (LV*)Dm, 16, 0, 0);
      return;
    }
    const int kg = k0 + V * 64;
    const int h  = s >> 1;
    const bool isA = !(s & 1);
    uint16_t* dst = (isA ? As : Bs) + (V & 1) * 16384 + (h * 128 + w * 16) * 64;
    if (isA) {
      const bool inX = (kg < 256);
      const uint16_t* src0 = inX ? (pXr + (size_t)(h * 128) * 256 + kg)
                                 : (pHr + (size_t)(h * 128) * 1024 + (kg - 256));
      const int rs = inX ? 256 : 1024;
      __builtin_amdgcn_global_load_lds((GV*)src0,            (LV*)dst,            16, 0, 0);
      __builtin_amdgcn_global_load_lds((GV*)(src0 + 8 * rs), (LV*)(dst + 8 * 64), 16, 0, 0);
    } else {
      const uint16_t* src0 = pWr + (size_t)(h * 128) * (size_t)KTOT + kg;
      __builtin_amdgcn_global_load_lds((GV*)src0,              (LV*)dst,            16, 0, 0);
      __builtin_amdgcn_global_load_lds((GV*)(src0 + 8 * KTOT), (LV*)(dst + 8 * 64), 16, 0, 0);
    }
  };

  f32x4 acc[4][2][4];   // [phase][Mfrag][gate]
#pragma unroll
  for (int p = 0; p < 4; p++)
#pragma unroll
    for (int i = 0; i < 2; i++)
#pragma unroll
      for (int n = 0; n < 4; n++) acc[p][i][n] = (f32x4){0.f, 0.f, 0.f, 0.f};

  // prologue: stage tile 0 fully; land s0,s1; keep s2,s3 in flight
  stage_half(0, 0); stage_half(0, 1); stage_half(0, 2); stage_half(0, 3);
  asm volatile("s_waitcnt vmcnt(4)" ::: "memory");
  __builtin_amdgcn_s_barrier();

  const int arow = (qr * 32 + l15) * 64;   // +i*1024, +8192 for A-h1
  const int brow = (qc * 64 + l15) * 64;   // +n*1024, +8192 for B-h1
  const int cc0  = (quad ^ e7) * 8;        // swizzled chunk, ks=0
  const int cc1  = ((4 + quad) ^ e7) * 8;  // swizzled chunk, ks=1

  for (int T = 0; T < NT; T++) {
    const uint16_t* Ab = As + (T & 1) * 16384;
    const uint16_t* Bb = Bs + (T & 1) * 16384;
    short8 a0[2][2], a1[2][2], bf[4][2];

    // ---- phase 0: quadrant (A0,B0) ----
#pragma unroll
    for (int i = 0; i < 2; i++) {
      a0[i][0] = *(const short8*)(Ab + arow + i * 1024 + cc0);
      a0[i][1] = *(const short8*)(Ab + arow + i * 1024 + cc1);
    }
#pragma unroll
    for (int n = 0; n < 4; n++) {
      bf[n][0] = *(const short8*)(Bb + brow + n * 1024 + cc0);
      bf[n][1] = *(const short8*)(Bb + brow + n * 1024 + cc1);
    }
    stage_half(T + 1, 0);
    asm volatile("s_waitcnt lgkmcnt(0)" ::: "memory");
    __builtin_amdgcn_sched_barrier(0);
    __builtin_amdgcn_s_setprio(1);
#pragma unroll
    for (int i = 0; i < 2; i++)
#pragma unroll
      for (int n = 0; n < 4; n++) {
        acc[0][i][n] = __builtin_amdgcn_mfma_f32_16x16x32_bf16(a0[i][0], bf[n][0], acc[0][i][n], 0, 0, 0);
        acc[0][i][n] = __builtin_amdgcn_mfma_f32_16x16x32_bf16(a0[i][1], bf[n][1], acc[0][i][n], 0, 0, 0);
      }
    __builtin_amdgcn_s_setprio(0);
    asm volatile("s_waitcnt vmcnt(4)" ::: "memory");   // this tile's A-h1 landed
    __builtin_amdgcn_s_barrier();                      // B1

    // ---- phase 1: quadrant (A1,B0) ----
#pragma unroll
    for (int i = 0; i < 2; i++) {
      a1[i][0] = *(const short8*)(Ab + 8192 + arow + i * 1024 + cc0);
      a1[i][1] = *(const short8*)(Ab + 8192 + arow + i * 1024 + cc1);
    }
    stage_half(T + 1, 1);
    asm volatile("s_waitcnt lgkmcnt(0)" ::: "memory");
    __builtin_amdgcn_sched_barrier(0);
    __builtin_amdgcn_s_setprio(1);
#pragma unroll
    for (int i = 0; i < 2; i++)
#pragma unroll
      for (int n = 0; n < 4; n++) {
        acc[1][i][n] = __builtin_amdgcn_mfma_f32_16x16x32_bf16(a1[i][0], bf[n][0], acc[1][i][n], 0, 0, 0);
        acc[1][i][n] = __builtin_amdgcn_mfma_f32_16x16x32_bf16(a1[i][1], bf[n][1], acc[1][i][n], 0, 0, 0);
      }
    __builtin_amdgcn_s_setprio(0);
    asm volatile("s_waitcnt vmcnt(4)" ::: "memory");   // this tile's B-h1 landed
    __builtin_amdgcn_s_barrier();                      // B2

    // ---- phases 2+3: quadrants (A1,B1) then (A0,B1), one region ----
#pragma unroll
    for (int n = 0; n < 4; n++) {
      bf[n][0] = *(const short8*)(Bb + 8192 + brow + n * 1024 + cc0);
      bf[n][1] = *(const short8*)(Bb + 8192 + brow + n * 1024 + cc1);
    }
    stage_half(T + 1, 2);
    asm volatile("s_waitcnt lgkmcnt(0)" ::: "memory");
    __builtin_amdgcn_sched_barrier(0);
    __builtin_amdgcn_s_setprio(1);
#pragma unroll
    for (int i = 0; i < 2; i++)
#pragma unroll
      for (int n = 0; n < 4; n++) {
        acc[2][i][n] = __builtin_amdgcn_mfma_f32_16x16x32_bf16(a1[i][0], bf[n][0], acc[2][i][n], 0, 0, 0);
        acc[2][i][n] = __builtin_amdgcn_mfma_f32_16x16x32_bf16(a1[i][1], bf[n][1], acc[2][i][n], 0, 0, 0);
      }
    __builtin_amdgcn_s_setprio(0);
    stage_half(T + 1, 3);
    __builtin_amdgcn_s_setprio(1);
#pragma unroll
    for (int i = 0; i < 2; i++)
#pragma unroll
      for (int n = 0; n < 4; n++) {
        acc[3][i][n] = __builtin_amdgcn_mfma_f32_16x16x32_bf16(a0[i][0], bf[n][0], acc[3][i][n], 0, 0, 0);
        acc[3][i][n] = __builtin_amdgcn_mfma_f32_16x16x32_bf16(a0[i][1], bf[n][1], acc[3][i][n], 0, 0, 0);
      }
    __builtin_amdgcn_s_setprio(0);
    asm volatile("s_waitcnt vmcnt(4)" ::: "memory");   // next tile's s0,s1 landed
    __builtin_amdgcn_s_barrier();                      // B3
  }
  asm volatile("s_waitcnt vmcnt(0)" ::: "memory");     // drain tail dummies once

  // Epilogue: per phase p, wave's C-chunk = rows ah*128+qr*32..+32,
  // cols bh*128+qc*64..+64 (n = gate). C/D: col=lane&15, row=quad*4+reg [m89]
#pragma unroll
  for (int p = 0; p < 4; p++) {
    const int ah = (p == 1 || p == 2) ? 1 : 0;
    const int bh = p >> 1;
    const int u  = ((bn >> 6) + bh * 2 + qc) * 16 + l15;
    const int jb = bn + bh * 128 + qc * 64 + l15;
    const float b_i = bias[jb];
    const float b_f = bias[jb + 16];
    const float b_g = bias[jb + 32];
    const float b_o = bias[jb + 48];
#pragma unroll
    for (int i = 0; i < 2; i++) {
#pragma unroll
      for (int r = 0; r < 4; r++) {
        const int row = bm + ah * 128 + qr * 32 + i * 16 + quad * 4 + r;
        const size_t idx = (size_t)row * 1024 + u;
        uint16_t hv;
        if (smask[row - bm]) {
          const float gi = acc[p][i][0][r] + b_i;
          const float gf = acc[p][i][1][r] + b_f;
          const float gg = acc[p][i][2][r] + b_g;
          const float go = acc[p][i][3][r] + b_o;
          const float cn = sigmf_(gf) * Cst[idx] + sigmf_(gi) * tanhf_(gg);
          Cst[idx] = cn;
          hv = f2bf(sigmf_(go) * tanhf_(cn));
        } else {
          hv = Hin[idx];        // state frozen; Hout is a different buffer
        }
        Hout[idx] = hv;
      }
    }
  }
}

// -------------------------------------------------------------------------
// h2n + outputs (+ optional fused embed for the NEXT step's X):
// raw = h @ h2n_w.T + h2n_b (one wave per track). Butterfly reduce leaves the
// full sums in ALL lanes; lane0 writes outputs; all lanes embed next X.
// -------------------------------------------------------------------------
__global__ __launch_bounds__(256) void h2n_pos(
    const uint16_t* __restrict__ H, const float* __restrict__ w5, const float* __restrict__ b5,
    const float* __restrict__ obs1, const float* __restrict__ obs2,
    float* __restrict__ outrel, float* __restrict__ outpos,
    const float* __restrict__ pprev, const float* __restrict__ ew,
    const float* __restrict__ eb, uint16_t* __restrict__ Xnext, int do_embed)
{
  const int lane  = threadIdx.x & 63;
  const int track = blockIdx.x * 4 + (threadIdx.x >> 6);

  const uint16_t* hrow = H + (size_t)track * 1024 + lane * 16;
  const short8 v0 = *(const short8*)(hrow);
  const short8 v1 = *(const short8*)(hrow + 8);
  float hv[16];
#pragma unroll
  for (int j = 0; j < 8; j++) {
    hv[j]     = bf2f((uint16_t)v0[j]);
    hv[8 + j] = bf2f((uint16_t)v1[j]);
  }
  const int kb = lane * 16;
  float p[5];
#pragma unroll
  for (int o = 0; o < 5; o++) {
    const float* wr = w5 + (size_t)o * 1024 + kb;
    float s = 0.f;
#pragma unroll
    for (int j = 0; j < 16; j++) s += hv[j] * wr[j];
    p[o] = s;
  }
#pragma unroll
  for (int o = 0; o < 5; o++) {
    float v = p[o];
    v += __shfl_xor(v, 32); v += __shfl_xor(v, 16); v += __shfl_xor(v, 8);
    v += __shfl_xor(v, 4);  v += __shfl_xor(v, 2);  v += __shfl_xor(v, 1);
    p[o] = v;
  }
  // all lanes hold the full sums now
  const float o1x = obs1[track * 2];
  const float o2x = obs2[track * 2];
  const float o2y = obs2[track * 2 + 1];
  const bool msk = !((o1x != o1x) || (o2x != o2x));
  float n0 = p[0] + b5[0];
  float n1 = p[1] + b5[1];
  float n2 = 0.01f + 0.2f * sigmf_(p[2] + b5[2]);
  float n3 = 0.01f + 0.2f * sigmf_(p[3] + b5[3]);
  float n4 = 0.7f  * sigmf_(p[4] + b5[4]);
  if (!msk) {
    const float qn = __uint_as_float(0x7fc00000u);
    n0 = n1 = n2 = n3 = n4 = qn;
  }
  const float posx = o2x + n0;
  const float posy = o2y + n1;
  if (lane == 0) {
    float* rr = outrel + (size_t)track * 5;
    rr[0] = n0; rr[1] = n1; rr[2] = n2; rr[3] = n3; rr[4] = n4;
    outpos[track * 2]     = posx;
    outpos[track * 2 + 1] = posy;
  }
  if (do_embed) {
    const float vx = (posx - pprev[track * 2])     * 4.0f;
    const float vy = (posy - pprev[track * 2 + 1]) * 4.0f;
    uint16_t* xr = Xnext + (size_t)track * 256;
#pragma unroll
    for (int ii = 0; ii < 4; ii++) {
      const int j = ii * 64 + lane;
      float e = 0.f;
      if (j < 254) e = fmaxf(vx * ew[j * 2] + vy * ew[j * 2 + 1] + eb[j], 0.f);
      xr[j] = f2bf(e);   // NaN inputs -> fmax gives 0; row is masked anyway
    }
  }
}

// -------------------------------------------------------------------------
extern "C" void kernel_launch(void* const* d_in, const int* in_sizes, int n_in,
                              void* d_out, int out_size, void* d_ws, size_t ws_size,
                              hipStream_t stream)
{
  const float* observed = (const float*)d_in[0];
  const float* emb_w    = (const float*)d_in[1];
  const float* emb_b    = (const float*)d_in[2];
  const float* enc_wih  = (const float*)d_in[3];
  const float* enc_whh  = (const float*)d_in[4];
  const float* enc_b    = (const float*)d_in[5];
  const float* dec_wih  = (const float*)d_in[6];
  const float* dec_whh  = (const float*)d_in[7];
  const float* dec_b    = (const float*)d_in[8];
  const float* h2n_w    = (const float*)d_in[9];
  const float* h2n_b    = (const float*)d_in[10];
  // d_in[11] = n_predict (==12, fixed by setup)

  char* ws = (char*)d_ws;
  size_t off = 0;
  auto alloc = [&](size_t bytes) -> void* {
    size_t cur = (off + 255) & ~(size_t)255;
    off = cur + bytes;
    return (void*)(ws + cur);
  };
  uint16_t* WcatE = (uint16_t*)alloc((size_t)4096 * KTOT * 2);
  uint16_t* WcatD = (uint16_t*)alloc((size_t)4096 * KTOT * 2);
  float*    biasE = (float*)alloc(4096 * 4);
  float*    biasD = (float*)alloc(4096 * 4);
  float*    biasDT= (float*)alloc(4096 * 4);
  float*    h0    = (float*)alloc(1024 * 4);
  float*    c0    = (float*)alloc(1024 * 4);
  uint16_t* HA    = (uint16_t*)alloc((size_t)4096 * 1024 * 2);
  uint16_t* HB    = (uint16_t*)alloc((size_t)4096 * 1024 * 2);
  float*    Cst   = (float*)alloc((size_t)4096 * 1024 * 4);
  uint16_t* Xb    = (uint16_t*)alloc((size_t)4096 * 256 * 2);
  // optional batched encoder X (16 MB) — only if workspace allows
  const size_t xall_bytes = (size_t)8 * 4096 * 256 * 2;
  const bool use_xall = (off + 256 + xall_bytes) <= ws_size;
  uint16_t* Xall = use_xall ? (uint16_t*)alloc(xall_bytes) : nullptr;

  float* outrel = (float*)d_out;                     // (19, 4096, 5)
  float* outpos = outrel + (size_t)NOUT * 4096 * 5;  // (19, 4096, 2)

  prep_weights<<<4096, 256, 0, stream>>>(enc_wih, enc_whh, enc_b, dec_wih, dec_whh, dec_b,
                                         WcatE, WcatD, biasE, biasD, biasDT);
  init_h0<<<4, 256, 0, stream>>>(enc_wih, enc_b, h0, c0);
  fill_state<<<16384, 256, 0, stream>>>(h0, c0, HA, Cst);
  if (use_xall) {
    embed8<<<dim3(4096, 8), 256, 0, stream>>>(observed, emb_w, emb_b, Xall);
  }

  uint16_t* Hin = HA;
  uint16_t* Hout = HB;
  const dim3 ggrid(16, 16);

  // ---- encoder: 8 steps over observed pairs ----
  for (int t = 0; t < 8; t++) {
    const float* o1 = observed + (size_t)t * 4096 * 2;
    const float* o2 = observed + (size_t)(t + 1) * 4096 * 2;
    uint16_t* Xt = Xb;
    if (use_xall) {
      Xt = Xall + (size_t)t * 4096 * 256;
    } else {
      embed_k<<<4096, 256, 0, stream>>>(o1, o2, emb_w, emb_b, Xb);
    }
    gemm_lstm<<<ggrid, 512, 0, stream>>>(Xt, Hin, WcatE, biasE, Cst, Hout, o1, o2, 0, 1);
    const int de = (t == 7) ? 1 : 0;   // t==7 also embeds X for first decoder step
    h2n_pos<<<1024, 256, 0, stream>>>(Hout, h2n_w, h2n_b, o1, o2,
                                      outrel + (size_t)t * 4096 * 5,
                                      outpos + (size_t)t * 4096 * 2,
                                      outpos + (size_t)6 * 4096 * 2, emb_w, emb_b, Xb, de);
    uint16_t* tmp = Hin; Hin = Hout; Hout = tmp;
  }

  // ---- decoder tag cell (x one-hot folded into biasDT; k0=256 skips X) ----
  gemm_lstm<<<ggrid, 512, 0, stream>>>(nullptr, Hin, WcatD, biasDT, Cst, Hout,
                                       nullptr, nullptr, 256, 0);
  { uint16_t* tmp = Hin; Hin = Hout; Hout = tmp; }

  // ---- decoder: 11 steps; X comes from the previous step's fused h2n ----
  for (int s = 0; s < 11; s++) {
    const float* p1 = outpos + (size_t)(6 + s) * 4096 * 2;
    const float* p2 = outpos + (size_t)(7 + s) * 4096 * 2;
    gemm_lstm<<<ggrid, 512, 0, stream>>>(Xb, Hin, WcatD, biasD, Cst, Hout, p1, p2, 0, 1);
    const int de = (s < 10) ? 1 : 0;   // last step needs no next X
    h2n_pos<<<1024, 256, 0, stream>>>(Hout, h2n_w, h2n_b, p1, p2,
                                      outrel + (size_t)(8 + s) * 4096 * 5,
                                      outpos + (size_t)(8 + s) * 4096 * 2,
                                      p2, emb_w, emb_b, Xb, de);
    uint16_t* tmp = Hin; Hin = Hout; Hout = tmp;
  }
}

// Round 5
// 1222.979 us; speedup vs baseline: 1.0729x; 1.0104x over previous
//
#include <hip/hip_runtime.h>
#include <stdint.h>

// Problem constants (reference: EMB=256, HID=1024, N_TRACKS=4096, SEQ=9, n_predict=12)
#define NTRK 4096
#define HIDN 1024
#define EMBN 256
#define KTOT 1280   // EMB + HID
#define NOUT 19     // 8 enc + 11 dec steps

typedef __attribute__((ext_vector_type(8))) short short8;
typedef __attribute__((ext_vector_type(4))) float f32x4;

typedef __attribute__((address_space(1))) const void GV;
typedef __attribute__((address_space(3))) void LV;

__device__ __forceinline__ uint16_t f2bf(float f) {
  uint32_t u = __float_as_uint(f);
  u += 0x7fffu + ((u >> 16) & 1u);   // round-to-nearest-even
  return (uint16_t)(u >> 16);
}
__device__ __forceinline__ float bf2f(uint16_t v) {
  return __uint_as_float(((uint32_t)v) << 16);
}
// precise (setup only)
__device__ __forceinline__ float sigm(float x) { return 1.0f / (1.0f + expf(-x)); }
// fast (hot paths): v_exp + v_rcp; error ~1e-6, margin is 5.5x
__device__ __forceinline__ float sigmf_(float x) {
  return __builtin_amdgcn_rcpf(1.0f + __expf(-x));
}
__device__ __forceinline__ float tanhf_(float x) {
  return 2.0f * __builtin_amdgcn_rcpf(1.0f + __expf(-2.0f * x)) - 1.0f;
}

// -------------------------------------------------------------------------
// Weight prep (16-unit gate groups): permuted row j' = q*64 + gate*16 + u16
// maps to original row gate*1024 + (q*16+u16). A 64-wide N-slab holds the
// 4 gates (i,f,g,o) of 16 hidden units -> LSTM pointwise is lane-local.
// Wih|Whh concatenated into one [4096][1280] bf16 row (single stride).
// -------------------------------------------------------------------------
__global__ __launch_bounds__(256) void prep_weights(
    const float* __restrict__ encWih, const float* __restrict__ encWhh,
    const float* __restrict__ encB,
    const float* __restrict__ decWih, const float* __restrict__ decWhh,
    const float* __restrict__ decB,
    uint16_t* __restrict__ WcatE, uint16_t* __restrict__ WcatD,
    float* __restrict__ biasE, float* __restrict__ biasD, float* __restrict__ biasDT)
{
  const int jp = blockIdx.x;                 // permuted row 0..4095
  const int q = jp >> 6, r = jp & 63;
  const int gate = r >> 4, l16 = r & 15;
  const int u = q * 16 + l16;
  const int orig = gate * 1024 + u;
  const int t = threadIdx.x;                 // 0..255

  WcatE[(size_t)jp * KTOT + t] = f2bf(encWih[(size_t)orig * 256 + t]);
  WcatD[(size_t)jp * KTOT + t] = f2bf(decWih[(size_t)orig * 256 + t]);
#pragma unroll
  for (int c = 0; c < 4; c++) {
    WcatE[(size_t)jp * KTOT + 256 + c * 256 + t] = f2bf(encWhh[(size_t)orig * 1024 + c * 256 + t]);
    WcatD[(size_t)jp * KTOT + 256 + c * 256 + t] = f2bf(decWhh[(size_t)orig * 1024 + c * 256 + t]);
  }
  if (t == 0) {
    biasE[jp]  = encB[orig];
    biasD[jp]  = decB[orig];
    biasDT[jp] = decB[orig] + decWih[(size_t)orig * 256 + 255]; // dec tag one-hot col 255
  }
}

// Enc-tag cell with h=c=0: gates identical for all tracks -> closed form.
__global__ void init_h0(const float* __restrict__ encWih, const float* __restrict__ encB,
                        float* __restrict__ h0, float* __restrict__ c0)
{
  const int u = blockIdx.x * 256 + threadIdx.x;   // 0..1023
  if (u >= 1024) return;
  const float gi = encWih[(size_t)(u) * 256 + 254]        + encB[u];
  const float gg = encWih[(size_t)(2048 + u) * 256 + 254] + encB[2048 + u];
  const float go = encWih[(size_t)(3072 + u) * 256 + 254] + encB[3072 + u];
  const float c = sigm(gi) * tanhf(gg);   // sigm(gf)*0 + ...
  c0[u] = c;
  h0[u] = sigm(go) * tanhf(c);
}

__global__ void fill_state(const float* __restrict__ h0, const float* __restrict__ c0,
                           uint16_t* __restrict__ H, float* __restrict__ Cst)
{
  const size_t i = (size_t)blockIdx.x * 256 + threadIdx.x;  // 4096*1024 total
  const int u = (int)(i & 1023);
  H[i] = f2bf(h0[u]);
  Cst[i] = c0[u];
}

// embed fallback for one encoder step (if workspace can't hold Xall)
__global__ __launch_bounds__(256) void embed_k(
    const float* __restrict__ o1, const float* __restrict__ o2,
    const float* __restrict__ ew, const float* __restrict__ eb,
    uint16_t* __restrict__ X)
{
  const int trk = blockIdx.x;
  const int j = threadIdx.x;
  const float vx = (o2[trk * 2]     - o1[trk * 2])     * 4.0f;
  const float vy = (o2[trk * 2 + 1] - o1[trk * 2 + 1]) * 4.0f;
  float e = 0.f;
  if (j < 254) e = fmaxf(vx * ew[j * 2] + vy * ew[j * 2 + 1] + eb[j], 0.f);
  X[(size_t)trk * 256 + j] = f2bf(e);
}

// All 8 encoder embeds in one dispatch (inputs known upfront).
__global__ __launch_bounds__(256) void embed8(
    const float* __restrict__ observed, const float* __restrict__ ew,
    const float* __restrict__ eb, uint16_t* __restrict__ Xall)
{
  const int t = blockIdx.y;          // 0..7
  const int trk = blockIdx.x;
  const int j = threadIdx.x;
  const float* o1 = observed + ((size_t)t * 4096 + trk) * 2;
  const float* o2 = o1 + 4096 * 2;
  const float vx = (o2[0] - o1[0]) * 4.0f;
  const float vy = (o2[1] - o1[1]) * 4.0f;
  float e = 0.f;
  if (j < 254) e = fmaxf(vx * ew[j * 2] + vy * ew[j * 2 + 1] + eb[j], 0.f);
  Xall[((size_t)t * 4096 + trk) * 256 + j] = f2bf(e);
}

// -------------------------------------------------------------------------
// Fused LSTM-cell GEMM — 256x256 tile, 8 waves, BK=64, double-buffered LDS,
// 3 barriers/K-tile (R3), XCD-L2-resident weights (R4).
// R5: REMOVED the manual lgkmcnt(0)+sched_barrier fence before each MFMA
// cluster. The ds_reads are plain C++ loads, so the compiler tracks them
// and emits fine-grained per-MFMA lgkmcnt(N) waits (G7/m97) — reads for
// fragment n+1 stay in flight while MFMA n executes, overlapping the LDS
// pipe (~2300cy/tile) with the matrix pipe (~2480cy/tile) instead of
// serializing them (~5300cy/tile, the R4 bottleneck).
// Sync points are pinned with sched_barrier(0) fences AROUND each
// s_barrier only: no memory op or MFMA may migrate across a barrier.
// WAR safety without the explicit drain: every ds_read result is consumed
// by an MFMA before the next barrier, so the compiler's own lgkm waits
// guarantee the reads returned before any wave crosses and re-stages.
// vmcnt cadence unchanged (audited R3/R4):
//   entering tile T outstanding = {T.s2,T.s3}; p0 +s0 -> vmcnt(4) retires
//   T.s2 (A-h1); p1 +s1 -> vmcnt(4) retires T.s3 (B-h1); p2+3 +s2,+s3 ->
//   vmcnt(4) retires (T+1).s0,s1. Never drained in the main loop.
// XCD mapping: xcd=bid&7; each XCD owns 8 bm x 4 bn -> 2.56MB weight
// panel, L2-resident and identical across all 20 steps (R4: FETCH -28%).
// -------------------------------------------------------------------------
__global__ __launch_bounds__(512, 2) void gemm_lstm(
    const uint16_t* __restrict__ X,    const uint16_t* __restrict__ Hin,
    const uint16_t* __restrict__ Wcat, const float* __restrict__ bias,
    float* __restrict__ Cst,           uint16_t* __restrict__ Hout,
    const float* __restrict__ obs1,    const float* __restrict__ obs2,
    int k0, int maskmode)
{
  __shared__ uint16_t As[2 * 16384];   // [buf][256 rows][64 k]
  __shared__ uint16_t Bs[2 * 16384];
  __shared__ uint16_t Dm[512];         // dummy stage target (tail cadence)
  __shared__ uint8_t  smask[256];

  const int tid  = threadIdx.x;
  const int w    = tid >> 6;          // wave 0..7
  const int lane = tid & 63;
  const int qr   = w & 3;             // within-quadrant 32-row chunk
  const int qc   = w >> 2;            // within-quadrant 64-col half
  const int quad = lane >> 4;
  const int l15  = lane & 15;
  const int e7   = l15 & 7;

  // XCD-bijective mapping: xcd = bid&7 (round-robin dispatch), 32 tiles/XCD
  // arranged 8 bm-strips x 4 bn-strips -> weights L2-resident per XCD.
  const int bid = blockIdx.y * 16 + blockIdx.x;
  const int xcd = bid & 7;
  const int j   = bid >> 3;           // 0..31
  const int bmS = (xcd >> 2) * 8 + (j >> 2);
  const int bnS = (xcd & 3) * 4 + (j & 3);
  const int bm  = bmS * 256;          // track rows
  const int bn  = bnS * 256;          // permuted gate cols

  const int NT = (KTOT - k0) >> 6;    // 20 (normal) or 16 (tag step)

  if (tid < 256) {
    bool m = true;
    if (maskmode) {
      const float a = obs1[(bm + tid) * 2];
      const float b = obs2[(bm + tid) * 2];
      m = !((a != a) || (b != b));
    }
    smask[tid] = m ? 1 : 0;
  }

  // Staging geometry: half-tile = 128 rows x 64 k (16 KB) = 2 gload_lds/wave.
  // Instr j covers rows base + w*16 + j*8 + (lane>>3), source chunk swizzled
  // by (lane&7)^(lane>>3) so that LDS(r, c) = G(r, c ^ (r&7)).
  const int srow = w * 16 + (lane >> 3);
  const int sch  = ((lane & 7) ^ (lane >> 3)) * 8;   // elements
  const uint16_t* pXr = X ? X + (size_t)(bm + srow) * 256 + sch : (const uint16_t*)0;
  const uint16_t* pHr = Hin  + (size_t)(bm + srow) * 1024 + sch;
  const uint16_t* pWr = Wcat + (size_t)(bn + srow) * (size_t)KTOT + sch;

  auto stage_half = [&](int V, int s) {   // s: 0=A-h0, 1=B-h0, 2=A-h1, 3=B-h1
    if (V >= NT) {                        // tail: keep vmcnt cadence exact
      const GV* dsrc = (GV*)(Wcat + (size_t)tid * 8);
      __builtin_amdgcn_global_load_lds(dsrc, (LV*)Dm, 16, 0, 0);
      __builtin_amdgcn_global_load_lds(dsrc, (LV*)Dm, 16, 0, 0);
      return;
    }
    const int kg = k0 + V * 64;
    const int h  = s >> 1;
    const bool isA = !(s & 1);
    uint16_t* dst = (isA ? As : Bs) + (V & 1) * 16384 + (h * 128 + w * 16) * 64;
    if (isA) {
      const bool inX = (kg < 256);
      const uint16_t* src0 = inX ? (pXr + (size_t)(h * 128) * 256 + kg)
                                 : (pHr + (size_t)(h * 128) * 1024 + (kg - 256));
      const int rs = inX ? 256 : 1024;
      __builtin_amdgcn_global_load_lds((GV*)src0,            (LV*)dst,            16, 0, 0);
      __builtin_amdgcn_global_load_lds((GV*)(src0 + 8 * rs), (LV*)(dst + 8 * 64), 16, 0, 0);
    } else {
      const uint16_t* src0 = pWr + (size_t)(h * 128) * (size_t)KTOT + kg;
      __builtin_amdgcn_global_load_lds((GV*)src0,              (LV*)dst,            16, 0, 0);
      __builtin_amdgcn_global_load_lds((GV*)(src0 + 8 * KTOT), (LV*)(dst + 8 * 64), 16, 0, 0);
    }
  };

  // barrier with scheduling pinned on both sides; counted vmcnt(N) first
  auto sync_n = [&](int n) {
    __builtin_amdgcn_sched_barrier(0);
    if (n == 4) asm volatile("s_waitcnt vmcnt(4)" ::: "memory");
    __builtin_amdgcn_s_barrier();
    __builtin_amdgcn_sched_barrier(0);
  };

  f32x4 acc[4][2][4];   // [phase][Mfrag][gate]
#pragma unroll
  for (int p = 0; p < 4; p++)
#pragma unroll
    for (int i = 0; i < 2; i++)
#pragma unroll
      for (int n = 0; n < 4; n++) acc[p][i][n] = (f32x4){0.f, 0.f, 0.f, 0.f};

  // prologue: stage tile 0 fully; land s0,s1; keep s2,s3 in flight
  stage_half(0, 0); stage_half(0, 1); stage_half(0, 2); stage_half(0, 3);
  sync_n(4);

  const int arow = (qr * 32 + l15) * 64;   // +i*1024, +8192 for A-h1
  const int brow = (qc * 64 + l15) * 64;   // +n*1024, +8192 for B-h1
  const int cc0  = (quad ^ e7) * 8;        // swizzled chunk, ks=0
  const int cc1  = ((4 + quad) ^ e7) * 8;  // swizzled chunk, ks=1

  for (int T = 0; T < NT; T++) {
    const uint16_t* Ab = As + (T & 1) * 16384;
    const uint16_t* Bb = Bs + (T & 1) * 16384;
    short8 a0[2][2], a1[2][2], bf[4][2];

    // ---- phase 0: quadrant (A0,B0) ----
#pragma unroll
    for (int i = 0; i < 2; i++) {
      a0[i][0] = *(const short8*)(Ab + arow + i * 1024 + cc0);
      a0[i][1] = *(const short8*)(Ab + arow + i * 1024 + cc1);
    }
#pragma unroll
    for (int n = 0; n < 4; n++) {
      bf[n][0] = *(const short8*)(Bb + brow + n * 1024 + cc0);
      bf[n][1] = *(const short8*)(Bb + brow + n * 1024 + cc1);
    }
    stage_half(T + 1, 0);
    __builtin_amdgcn_s_setprio(1);
#pragma unroll
    for (int i = 0; i < 2; i++)
#pragma unroll
      for (int n = 0; n < 4; n++) {
        acc[0][i][n] = __builtin_amdgcn_mfma_f32_16x16x32_bf16(a0[i][0], bf[n][0], acc[0][i][n], 0, 0, 0);
        acc[0][i][n] = __builtin_amdgcn_mfma_f32_16x16x32_bf16(a0[i][1], bf[n][1], acc[0][i][n], 0, 0, 0);
      }
    __builtin_amdgcn_s_setprio(0);
    sync_n(4);                                         // B1: this tile's A-h1 landed

    // ---- phase 1: quadrant (A1,B0) ----
#pragma unroll
    for (int i = 0; i < 2; i++) {
      a1[i][0] = *(const short8*)(Ab + 8192 + arow + i * 1024 + cc0);
      a1[i][1] = *(const short8*)(Ab + 8192 + arow + i * 1024 + cc1);
    }
    stage_half(T + 1, 1);
    __builtin_amdgcn_s_setprio(1);
#pragma unroll
    for (int i = 0; i < 2; i++)
#pragma unroll
      for (int n = 0; n < 4; n++) {
        acc[1][i][n] = __builtin_amdgcn_mfma_f32_16x16x32_bf16(a1[i][0], bf[n][0], acc[1][i][n], 0, 0, 0);
        acc[1][i][n] = __builtin_amdgcn_mfma_f32_16x16x32_bf16(a1[i][1], bf[n][1], acc[1][i][n], 0, 0, 0);
      }
    __builtin_amdgcn_s_setprio(0);
    sync_n(4);                                         // B2: this tile's B-h1 landed

    // ---- phases 2+3: quadrants (A1,B1) then (A0,B1), one region ----
#pragma unroll
    for (int n = 0; n < 4; n++) {
      bf[n][0] = *(const short8*)(Bb + 8192 + brow + n * 1024 + cc0);
      bf[n][1] = *(const short8*)(Bb + 8192 + brow + n * 1024 + cc1);
    }
    stage_half(T + 1, 2);
    __builtin_amdgcn_s_setprio(1);
#pragma unroll
    for (int i = 0; i < 2; i++)
#pragma unroll
      for (int n = 0; n < 4; n++) {
        acc[2][i][n] = __builtin_amdgcn_mfma_f32_16x16x32_bf16(a1[i][0], bf[n][0], acc[2][i][n], 0, 0, 0);
        acc[2][i][n] = __builtin_amdgcn_mfma_f32_16x16x32_bf16(a1[i][1], bf[n][1], acc[2][i][n], 0, 0, 0);
      }
    __builtin_amdgcn_s_setprio(0);
    stage_half(T + 1, 3);
    __builtin_amdgcn_s_setprio(1);
#pragma unroll
    for (int i = 0; i < 2; i++)
#pragma unroll
      for (int n = 0; n < 4; n++) {
        acc[3][i][n] = __builtin_amdgcn_mfma_f32_16x16x32_bf16(a0[i][0], bf[n][0], acc[3][i][n], 0, 0, 0);
        acc[3][i][n] = __builtin_amdgcn_mfma_f32_16x16x32_bf16(a0[i][1], bf[n][1], acc[3][i][n], 0, 0, 0);
      }
    __builtin_amdgcn_s_setprio(0);
    sync_n(4);                                         // B3: next tile's s0,s1 landed
  }
  asm volatile("s_waitcnt vmcnt(0)" ::: "memory");     // drain tail dummies once

  // Epilogue: per phase p, wave's C-chunk = rows ah*128+qr*32..+32,
  // cols bh*128+qc*64..+64 (n = gate). C/D: col=lane&15, row=quad*4+reg [m89]
#pragma unroll
  for (int p = 0; p < 4; p++) {
    const int ah = (p == 1 || p == 2) ? 1 : 0;
    const int bh = p >> 1;
    const int u  = ((bn >> 6) + bh * 2 + qc) * 16 + l15;
    const int jb = bn + bh * 128 + qc * 64 + l15;
    const float b_i = bias[jb];
    const float b_f = bias[jb + 16];
    const float b_g = bias[jb + 32];
    const float b_o = bias[jb + 48];
#pragma unroll
    for (int i = 0; i < 2; i++) {
#pragma unroll
      for (int r = 0; r < 4; r++) {
        const int row = bm + ah * 128 + qr * 32 + i * 16 + quad * 4 + r;
        const size_t idx = (size_t)row * 1024 + u;
        uint16_t hv;
        if (smask[row - bm]) {
          const float gi = acc[p][i][0][r] + b_i;
          const float gf = acc[p][i][1][r] + b_f;
          const float gg = acc[p][i][2][r] + b_g;
          const float go = acc[p][i][3][r] + b_o;
          const float cn = sigmf_(gf) * Cst[idx] + sigmf_(gi) * tanhf_(gg);
          Cst[idx] = cn;
          hv = f2bf(sigmf_(go) * tanhf_(cn));
        } else {
          hv = Hin[idx];        // state frozen; Hout is a different buffer
        }
        Hout[idx] = hv;
      }
    }
  }
}

// -------------------------------------------------------------------------
// h2n + outputs (+ optional fused embed for the NEXT step's X):
// raw = h @ h2n_w.T + h2n_b (one wave per track). Butterfly reduce leaves the
// full sums in ALL lanes; lane0 writes outputs; all lanes embed next X.
// -------------------------------------------------------------------------
__global__ __launch_bounds__(256) void h2n_pos(
    const uint16_t* __restrict__ H, const float* __restrict__ w5, const float* __restrict__ b5,
    const float* __restrict__ obs1, const float* __restrict__ obs2,
    float* __restrict__ outrel, float* __restrict__ outpos,
    const float* __restrict__ pprev, const float* __restrict__ ew,
    const float* __restrict__ eb, uint16_t* __restrict__ Xnext, int do_embed)
{
  const int lane  = threadIdx.x & 63;
  const int track = blockIdx.x * 4 + (threadIdx.x >> 6);

  const uint16_t* hrow = H + (size_t)track * 1024 + lane * 16;
  const short8 v0 = *(const short8*)(hrow);
  const short8 v1 = *(const short8*)(hrow + 8);
  float hv[16];
#pragma unroll
  for (int j = 0; j < 8; j++) {
    hv[j]     = bf2f((uint16_t)v0[j]);
    hv[8 + j] = bf2f((uint16_t)v1[j]);
  }
  const int kb = lane * 16;
  float p[5];
#pragma unroll
  for (int o = 0; o < 5; o++) {
    const float* wr = w5 + (size_t)o * 1024 + kb;
    float s = 0.f;
#pragma unroll
    for (int j = 0; j < 16; j++) s += hv[j] * wr[j];
    p[o] = s;
  }
#pragma unroll
  for (int o = 0; o < 5; o++) {
    float v = p[o];
    v += __shfl_xor(v, 32); v += __shfl_xor(v, 16); v += __shfl_xor(v, 8);
    v += __shfl_xor(v, 4);  v += __shfl_xor(v, 2);  v += __shfl_xor(v, 1);
    p[o] = v;
  }
  // all lanes hold the full sums now
  const float o1x = obs1[track * 2];
  const float o2x = obs2[track * 2];
  const float o2y = obs2[track * 2 + 1];
  const bool msk = !((o1x != o1x) || (o2x != o2x));
  float n0 = p[0] + b5[0];
  float n1 = p[1] + b5[1];
  float n2 = 0.01f + 0.2f * sigmf_(p[2] + b5[2]);
  float n3 = 0.01f + 0.2f * sigmf_(p[3] + b5[3]);
  float n4 = 0.7f  * sigmf_(p[4] + b5[4]);
  if (!msk) {
    const float qn = __uint_as_float(0x7fc00000u);
    n0 = n1 = n2 = n3 = n4 = qn;
  }
  const float posx = o2x + n0;
  const float posy = o2y + n1;
  if (lane == 0) {
    float* rr = outrel + (size_t)track * 5;
    rr[0] = n0; rr[1] = n1; rr[2] = n2; rr[3] = n3; rr[4] = n4;
    outpos[track * 2]     = posx;
    outpos[track * 2 + 1] = posy;
  }
  if (do_embed) {
    const float vx = (posx - pprev[track * 2])     * 4.0f;
    const float vy = (posy - pprev[track * 2 + 1]) * 4.0f;
    uint16_t* xr = Xnext + (size_t)track * 256;
#pragma unroll
    for (int ii = 0; ii < 4; ii++) {
      const int j = ii * 64 + lane;
      float e = 0.f;
      if (j < 254) e = fmaxf(vx * ew[j * 2] + vy * ew[j * 2 + 1] + eb[j], 0.f);
      xr[j] = f2bf(e);   // NaN inputs -> fmax gives 0; row is masked anyway
    }
  }
}

// -------------------------------------------------------------------------
extern "C" void kernel_launch(void* const* d_in, const int* in_sizes, int n_in,
                              void* d_out, int out_size, void* d_ws, size_t ws_size,
                              hipStream_t stream)
{
  const float* observed = (const float*)d_in[0];
  const float* emb_w    = (const float*)d_in[1];
  const float* emb_b    = (const float*)d_in[2];
  const float* enc_wih  = (const float*)d_in[3];
  const float* enc_whh  = (const float*)d_in[4];
  const float* enc_b    = (const float*)d_in[5];
  const float* dec_wih  = (const float*)d_in[6];
  const float* dec_whh  = (const float*)d_in[7];
  const float* dec_b    = (const float*)d_in[8];
  const float* h2n_w    = (const float*)d_in[9];
  const float* h2n_b    = (const float*)d_in[10];
  // d_in[11] = n_predict (==12, fixed by setup)

  char* ws = (char*)d_ws;
  size_t off = 0;
  auto alloc = [&](size_t bytes) -> void* {
    size_t cur = (off + 255) & ~(size_t)255;
    off = cur + bytes;
    return (void*)(ws + cur);
  };
  uint16_t* WcatE = (uint16_t*)alloc((size_t)4096 * KTOT * 2);
  uint16_t* WcatD = (uint16_t*)alloc((size_t)4096 * KTOT * 2);
  float*    biasE = (float*)alloc(4096 * 4);
  float*    biasD = (float*)alloc(4096 * 4);
  float*    biasDT= (float*)alloc(4096 * 4);
  float*    h0    = (float*)alloc(1024 * 4);
  float*    c0    = (float*)alloc(1024 * 4);
  uint16_t* HA    = (uint16_t*)alloc((size_t)4096 * 1024 * 2);
  uint16_t* HB    = (uint16_t*)alloc((size_t)4096 * 1024 * 2);
  float*    Cst   = (float*)alloc((size_t)4096 * 1024 * 4);
  uint16_t* Xb    = (uint16_t*)alloc((size_t)4096 * 256 * 2);
  // optional batched encoder X (16 MB) — only if workspace allows
  const size_t xall_bytes = (size_t)8 * 4096 * 256 * 2;
  const bool use_xall = (off + 256 + xall_bytes) <= ws_size;
  uint16_t* Xall = use_xall ? (uint16_t*)alloc(xall_bytes) : nullptr;

  float* outrel = (float*)d_out;                     // (19, 4096, 5)
  float* outpos = outrel + (size_t)NOUT * 4096 * 5;  // (19, 4096, 2)

  prep_weights<<<4096, 256, 0, stream>>>(enc_wih, enc_whh, enc_b, dec_wih, dec_whh, dec_b,
                                         WcatE, WcatD, biasE, biasD, biasDT);
  init_h0<<<4, 256, 0, stream>>>(enc_wih, enc_b, h0, c0);
  fill_state<<<16384, 256, 0, stream>>>(h0, c0, HA, Cst);
  if (use_xall) {
    embed8<<<dim3(4096, 8), 256, 0, stream>>>(observed, emb_w, emb_b, Xall);
  }

  uint16_t* Hin = HA;
  uint16_t* Hout = HB;
  const dim3 ggrid(16, 16);

  // ---- encoder: 8 steps over observed pairs ----
  for (int t = 0; t < 8; t++) {
    const float* o1 = observed + (size_t)t * 4096 * 2;
    const float* o2 = observed + (size_t)(t + 1) * 4096 * 2;
    uint16_t* Xt = Xb;
    if (use_xall) {
      Xt = Xall + (size_t)t * 4096 * 256;
    } else {
      embed_k<<<4096, 256, 0, stream>>>(o1, o2, emb_w, emb_b, Xb);
    }
    gemm_lstm<<<ggrid, 512, 0, stream>>>(Xt, Hin, WcatE, biasE, Cst, Hout, o1, o2, 0, 1);
    const int de = (t == 7) ? 1 : 0;   // t==7 also embeds X for first decoder step
    h2n_pos<<<1024, 256, 0, stream>>>(Hout, h2n_w, h2n_b, o1, o2,
                                      outrel + (size_t)t * 4096 * 5,
                                      outpos + (size_t)t * 4096 * 2,
                                      outpos + (size_t)6 * 4096 * 2, emb_w, emb_b, Xb, de);
    uint16_t* tmp = Hin; Hin = Hout; Hout = tmp;
  }

  // ---- decoder tag cell (x one-hot folded into biasDT; k0=256 skips X) ----
  gemm_lstm<<<ggrid, 512, 0, stream>>>(nullptr, Hin, WcatD, biasDT, Cst, Hout,
                                       nullptr, nullptr, 256, 0);
  { uint16_t* tmp = Hin; Hin = Hout; Hout = tmp; }

  // ---- decoder: 11 steps; X comes from the previous step's fused h2n ----
  for (int s = 0; s < 11; s++) {
    const float* p1 = outpos + (size_t)(6 + s) * 4096 * 2;
    const float* p2 = outpos + (size_t)(7 + s) * 4096 * 2;
    gemm_lstm<<<ggrid, 512, 0, stream>>>(Xb, Hin, WcatD, biasD, Cst, Hout, p1, p2, 0, 1);
    const int de = (s < 10) ? 1 : 0;   // last step needs no next X
    h2n_pos<<<1024, 256, 0, stream>>>(Hout, h2n_w, h2n_b, p1, p2,
                                      outrel + (size_t)(8 + s) * 4096 * 5,
                                      outpos + (size_t)(8 + s) * 4096 * 2,
                                      p2, emb_w, emb_b, Xb, de);
    uint16_t* tmp = Hin; Hin = Hout; Hout = tmp;
  }
}